// Round 1
// baseline (3072.917 us; speedup 1.0000x reference)
//
#include <hip/hip_runtime.h>

#define N_NODES 100000
#define N_EDGES 3200000
#define N_GRAPHS 64
#define HID 128

// ---------------- degree histogram ----------------
__global__ void deg_kernel(const int* __restrict__ dst, int* __restrict__ cnt, int e) {
    int i = blockIdx.x * blockDim.x + threadIdx.x;
    if (i < e) atomicAdd(&cnt[dst[i]], 1);
}

__global__ void dis_kernel(const int* __restrict__ cnt, float* __restrict__ dis,
                           float* __restrict__ selfc, int n) {
    int i = blockIdx.x * blockDim.x + threadIdx.x;
    if (i < n) {
        float d = (float)cnt[i] + 1.0f;
        dis[i] = rsqrtf(d);
        selfc[i] = 1.0f / d;
    }
}

// ---------------- 3-kernel exclusive scan (for CSR row_ptr) ----------------
__global__ void scan_block_sum(const int* __restrict__ cnt, int* __restrict__ bsum, int n) {
    __shared__ int sdata[16];
    int i = blockIdx.x * 1024 + threadIdx.x;
    int v = (i < n) ? cnt[i] : 0;
    #pragma unroll
    for (int off = 32; off > 0; off >>= 1) v += __shfl_down(v, off, 64);
    int wid = threadIdx.x >> 6, lane = threadIdx.x & 63;
    if (lane == 0) sdata[wid] = v;
    __syncthreads();
    if (threadIdx.x == 0) {
        int s = 0;
        for (int w = 0; w < 16; w++) s += sdata[w];
        bsum[blockIdx.x] = s;
    }
}

__global__ void scan_bsum(int* __restrict__ bsum, int* __restrict__ bexcl,
                          int* __restrict__ row_ptr_last, int nb) {
    if (threadIdx.x == 0 && blockIdx.x == 0) {
        int s = 0;
        for (int b = 0; b < nb; b++) { bexcl[b] = s; s += bsum[b]; }
        row_ptr_last[0] = s;  // row_ptr[N] == E
    }
}

__global__ void scan_final(const int* __restrict__ cnt, const int* __restrict__ bexcl,
                           int* __restrict__ row_ptr, int* __restrict__ fill, int n) {
    __shared__ int buf[1024];
    int t = threadIdx.x;
    int i = blockIdx.x * 1024 + t;
    int v = (i < n) ? cnt[i] : 0;
    buf[t] = v;
    __syncthreads();
    for (int off = 1; off < 1024; off <<= 1) {
        int x = (t >= off) ? buf[t - off] : 0;
        __syncthreads();
        buf[t] += x;
        __syncthreads();
    }
    int excl = buf[t] - v + bexcl[blockIdx.x];
    if (i < n) { row_ptr[i] = excl; fill[i] = excl; }
}

// ---------------- CSR bucket fill ----------------
__global__ void csr_fill(const int* __restrict__ src, const int* __restrict__ dst,
                         const float* __restrict__ dis, int* __restrict__ fill,
                         int* __restrict__ col, float* __restrict__ ew, int e) {
    int i = blockIdx.x * blockDim.x + threadIdx.x;
    if (i < e) {
        int s = src[i], d = dst[i];
        int pos = atomicAdd(&fill[d], 1);
        col[pos] = s;
        ew[pos] = dis[s] * dis[d];
    }
}

// ---------------- dense GEMM: out[N x 128] = A[N x K] @ W[K x 128] ----------------
template <int K>
__global__ __launch_bounds__(256) void gemm_kernel(const float* __restrict__ A,
                                                   const float* __restrict__ W,
                                                   float* __restrict__ out, int n) {
    __shared__ float4 Ws[K * 32];
    const float4* W4 = (const float4*)W;
    for (int i = threadIdx.x; i < K * 32; i += 256) Ws[i] = W4[i];
    __syncthreads();
    int r = blockIdx.x * 256 + threadIdx.x;
    if (r >= n) return;
    float4 acc[32];
    #pragma unroll
    for (int j = 0; j < 32; j++) acc[j] = make_float4(0.f, 0.f, 0.f, 0.f);
    const float4* Arow = (const float4*)(A + (size_t)r * K);
    #pragma unroll 2
    for (int k0 = 0; k0 < K / 4; k0++) {
        float4 a4 = Arow[k0];
        float av[4] = {a4.x, a4.y, a4.z, a4.w};
        #pragma unroll
        for (int kk = 0; kk < 4; kk++) {
            float a = av[kk];
            #pragma unroll
            for (int j = 0; j < 32; j++) {
                float4 w = Ws[(k0 * 4 + kk) * 32 + j];
                acc[j].x += a * w.x;
                acc[j].y += a * w.y;
                acc[j].z += a * w.z;
                acc[j].w += a * w.w;
            }
        }
    }
    float4* o = (float4*)(out + (size_t)r * HID);
    #pragma unroll
    for (int j = 0; j < 32; j++) o[j] = acc[j];
}

// ---------------- node-parallel aggregation: out = A_norm * hw + selfc.*hw + b, relu ----
__global__ __launch_bounds__(256) void agg_kernel(const float* __restrict__ hw,
                                                  const int* __restrict__ row_ptr,
                                                  const int* __restrict__ col,
                                                  const float* __restrict__ ew,
                                                  const float* __restrict__ selfc,
                                                  const float* __restrict__ bias,
                                                  float* __restrict__ out, int n) {
    int node = blockIdx.x * 4 + (threadIdx.x >> 6);
    if (node >= n) return;
    int lane = threadIdx.x & 63;
    int beg = row_ptr[node], end = row_ptr[node + 1];
    float ax = 0.f, ay = 0.f;
    for (int e = beg; e < end; e++) {
        int c = col[e];
        float w = ew[e];
        float2 v = *(const float2*)&hw[(size_t)c * HID + lane * 2];
        ax += w * v.x;
        ay += w * v.y;
    }
    float sc = selfc[node];
    float2 hs = *(const float2*)&hw[(size_t)node * HID + lane * 2];
    float2 b = *(const float2*)&bias[lane * 2];
    float ox = fmaxf(ax + sc * hs.x + b.x, 0.0f);
    float oy = fmaxf(ay + sc * hs.y + b.y, 0.0f);
    *(float2*)&out[(size_t)node * HID + lane * 2] = make_float2(ox, oy);
}

// ---------------- graph pooling ----------------
__global__ void gcount_kernel(const int* __restrict__ batch, int* __restrict__ gcnt, int n) {
    int i = blockIdx.x * blockDim.x + threadIdx.x;
    if (i < n) atomicAdd(&gcnt[batch[i]], 1);
}

__global__ __launch_bounds__(128) void pool_kernel(const float* __restrict__ h,
                                                   const int* __restrict__ batch,
                                                   float* __restrict__ pooled, int n) {
    int f = threadIdx.x;
    int n0 = blockIdx.x * 256;
    if (n0 >= n) return;
    int n1 = min(n0 + 256, n);
    float acc = 0.f;
    int cur = batch[n0];
    for (int i = n0; i < n1; i++) {
        int b = batch[i];
        if (b != cur) {
            atomicAdd(&pooled[cur * HID + f], acc);
            acc = 0.f;
            cur = b;
        }
        acc += h[(size_t)i * HID + f];
    }
    atomicAdd(&pooled[cur * HID + f], acc);
}

// ---------------- head: mean, dense 128->10, log_softmax ----------------
__global__ __launch_bounds__(128) void final_kernel(const float* __restrict__ pooled,
                                                    const int* __restrict__ gcnt,
                                                    const float* __restrict__ Wout,
                                                    const float* __restrict__ bout,
                                                    float* __restrict__ out) {
    __shared__ float p[HID];
    __shared__ float lg[10];
    __shared__ float lsum;
    int g = blockIdx.x, t = threadIdx.x;
    float c = fmaxf((float)gcnt[g], 1.0f);
    p[t] = pooled[g * HID + t] / c;
    __syncthreads();
    if (t < 10) {
        float s = bout[t];
        for (int f = 0; f < HID; f++) s += p[f] * Wout[f * 10 + t];
        lg[t] = s;
    }
    __syncthreads();
    if (t == 0) {
        float m = lg[0];
        for (int ci = 1; ci < 10; ci++) m = fmaxf(m, lg[ci]);
        float se = 0.f;
        for (int ci = 0; ci < 10; ci++) se += expf(lg[ci] - m);
        lsum = m + logf(se);
    }
    __syncthreads();
    if (t < 10) out[g * 10 + t] = lg[t] - lsum;
}

extern "C" void kernel_launch(void* const* d_in, const int* in_sizes, int n_in,
                              void* d_out, int out_size, void* d_ws, size_t ws_size,
                              hipStream_t stream) {
    const float* x = (const float*)d_in[0];
    const int* ei = (const int*)d_in[1];
    const int* batch = (const int*)d_in[2];
    const float* W[5] = {(const float*)d_in[3], (const float*)d_in[5], (const float*)d_in[7],
                         (const float*)d_in[9], (const float*)d_in[11]};
    const float* B[5] = {(const float*)d_in[4], (const float*)d_in[6], (const float*)d_in[8],
                         (const float*)d_in[10], (const float*)d_in[12]};
    const float* Wout = (const float*)d_in[13];
    const float* bout = (const float*)d_in[14];
    float* out = (float*)d_out;

    const int* src = ei;
    const int* dst = ei + N_EDGES;

    char* ws = (char*)d_ws;
    size_t off = 0;
    auto alloc = [&](size_t bytes) -> char* {
        char* p = ws + off;
        off = (off + bytes + 255) & ~(size_t)255;
        return p;
    };
    int* cnt = (int*)alloc(N_NODES * 4);
    float* pooled = (float*)alloc(N_GRAPHS * HID * 4);
    int* gcnt = (int*)alloc(N_GRAPHS * 4);
    size_t zero_span = off;  // cnt + pooled + gcnt get memset to 0
    int* row_ptr = (int*)alloc((N_NODES + 1) * 4);
    int* fill = (int*)alloc(N_NODES * 4);
    float* dis = (float*)alloc(N_NODES * 4);
    float* selfc = (float*)alloc(N_NODES * 4);
    int* bsum = (int*)alloc(128 * 4);
    int* bexcl = (int*)alloc(128 * 4);
    int* col = (int*)alloc((size_t)N_EDGES * 4);
    float* ew = (float*)alloc((size_t)N_EDGES * 4);
    float* h_a = (float*)alloc((size_t)N_NODES * HID * 4);
    float* h_b = (float*)alloc((size_t)N_NODES * HID * 4);

    hipMemsetAsync(d_ws, 0, zero_span, stream);

    int eb = (N_EDGES + 255) / 256;
    int nb = (N_NODES + 255) / 256;
    int sb = (N_NODES + 1023) / 1024;  // 98

    deg_kernel<<<eb, 256, 0, stream>>>(dst, cnt, N_EDGES);
    dis_kernel<<<nb, 256, 0, stream>>>(cnt, dis, selfc, N_NODES);
    scan_block_sum<<<sb, 1024, 0, stream>>>(cnt, bsum, N_NODES);
    scan_bsum<<<1, 64, 0, stream>>>(bsum, bexcl, row_ptr + N_NODES, sb);
    scan_final<<<sb, 1024, 0, stream>>>(cnt, bexcl, row_ptr, fill, N_NODES);
    csr_fill<<<eb, 256, 0, stream>>>(src, dst, dis, fill, col, ew, N_EDGES);

    int gb = (N_NODES + 255) / 256;
    int ab = (N_NODES + 3) / 4;

    // layer 1: K=8
    gemm_kernel<8><<<gb, 256, 0, stream>>>(x, W[0], h_b, N_NODES);
    agg_kernel<<<ab, 256, 0, stream>>>(h_b, row_ptr, col, ew, selfc, B[0], h_a, N_NODES);
    // layers 2..5: K=128
    for (int l = 1; l < 5; l++) {
        gemm_kernel<128><<<gb, 256, 0, stream>>>(h_a, W[l], h_b, N_NODES);
        agg_kernel<<<ab, 256, 0, stream>>>(h_b, row_ptr, col, ew, selfc, B[l], h_a, N_NODES);
    }

    gcount_kernel<<<nb, 256, 0, stream>>>(batch, gcnt, N_NODES);
    pool_kernel<<<(N_NODES + 255) / 256, 128, 0, stream>>>(h_a, batch, pooled, N_NODES);
    final_kernel<<<N_GRAPHS, 128, 0, stream>>>(pooled, gcnt, Wout, bout, out);
}

// Round 2
// 2130.595 us; speedup vs baseline: 1.4423x; 1.4423x over previous
//
#include <hip/hip_runtime.h>

#define N_NODES 100000
#define N_EDGES 3200000
#define N_GRAPHS 64
#define HID 128

// ---------------- degree histogram ----------------
__global__ void deg_kernel(const int* __restrict__ dst, int* __restrict__ cnt, int e) {
    int i = blockIdx.x * blockDim.x + threadIdx.x;
    if (i < e) atomicAdd(&cnt[dst[i]], 1);
}

__global__ void dis_kernel(const int* __restrict__ cnt, float* __restrict__ dis,
                           float* __restrict__ selfc, int n) {
    int i = blockIdx.x * blockDim.x + threadIdx.x;
    if (i < n) {
        float d = (float)cnt[i] + 1.0f;
        dis[i] = rsqrtf(d);
        selfc[i] = 1.0f / d;
    }
}

// ---------------- 3-kernel exclusive scan (for CSR row_ptr) ----------------
__global__ void scan_block_sum(const int* __restrict__ cnt, int* __restrict__ bsum, int n) {
    __shared__ int sdata[16];
    int i = blockIdx.x * 1024 + threadIdx.x;
    int v = (i < n) ? cnt[i] : 0;
    #pragma unroll
    for (int off = 32; off > 0; off >>= 1) v += __shfl_down(v, off, 64);
    int wid = threadIdx.x >> 6, lane = threadIdx.x & 63;
    if (lane == 0) sdata[wid] = v;
    __syncthreads();
    if (threadIdx.x == 0) {
        int s = 0;
        for (int w = 0; w < 16; w++) s += sdata[w];
        bsum[blockIdx.x] = s;
    }
}

__global__ void scan_bsum(int* __restrict__ bsum, int* __restrict__ bexcl,
                          int* __restrict__ row_ptr_last, int nb) {
    if (threadIdx.x == 0 && blockIdx.x == 0) {
        int s = 0;
        for (int b = 0; b < nb; b++) { bexcl[b] = s; s += bsum[b]; }
        row_ptr_last[0] = s;  // row_ptr[N] == E
    }
}

__global__ void scan_final(const int* __restrict__ cnt, const int* __restrict__ bexcl,
                           int* __restrict__ row_ptr, int* __restrict__ fill, int n) {
    __shared__ int buf[1024];
    int t = threadIdx.x;
    int i = blockIdx.x * 1024 + t;
    int v = (i < n) ? cnt[i] : 0;
    buf[t] = v;
    __syncthreads();
    for (int off = 1; off < 1024; off <<= 1) {
        int x = (t >= off) ? buf[t - off] : 0;
        __syncthreads();
        buf[t] += x;
        __syncthreads();
    }
    int excl = buf[t] - v + bexcl[blockIdx.x];
    if (i < n) { row_ptr[i] = excl; fill[i] = excl; }
}

// ---------------- CSR bucket fill ----------------
__global__ void csr_fill(const int* __restrict__ src, const int* __restrict__ dst,
                         const float* __restrict__ dis, int* __restrict__ fill,
                         int* __restrict__ col, float* __restrict__ ew, int e) {
    int i = blockIdx.x * blockDim.x + threadIdx.x;
    if (i < e) {
        int s = src[i], d = dst[i];
        int pos = atomicAdd(&fill[d], 1);
        col[pos] = s;
        ew[pos] = dis[s] * dis[d];
    }
}

// ---------------- dense GEMM: out[N x 128] = A[N x K] @ W[K x 128] ----------------
template <int K>
__global__ __launch_bounds__(256) void gemm_kernel(const float* __restrict__ A,
                                                   const float* __restrict__ W,
                                                   float* __restrict__ out, int n) {
    __shared__ float4 Ws[K * 32];
    const float4* W4 = (const float4*)W;
    for (int i = threadIdx.x; i < K * 32; i += 256) Ws[i] = W4[i];
    __syncthreads();
    int r = blockIdx.x * 256 + threadIdx.x;
    if (r >= n) return;
    float4 acc[32];
    #pragma unroll
    for (int j = 0; j < 32; j++) acc[j] = make_float4(0.f, 0.f, 0.f, 0.f);
    const float4* Arow = (const float4*)(A + (size_t)r * K);
    #pragma unroll 2
    for (int k0 = 0; k0 < K / 4; k0++) {
        float4 a4 = Arow[k0];
        float av[4] = {a4.x, a4.y, a4.z, a4.w};
        #pragma unroll
        for (int kk = 0; kk < 4; kk++) {
            float a = av[kk];
            #pragma unroll
            for (int j = 0; j < 32; j++) {
                float4 w = Ws[(k0 * 4 + kk) * 32 + j];
                acc[j].x += a * w.x;
                acc[j].y += a * w.y;
                acc[j].z += a * w.z;
                acc[j].w += a * w.w;
            }
        }
    }
    float4* o = (float4*)(out + (size_t)r * HID);
    #pragma unroll
    for (int j = 0; j < 32; j++) o[j] = acc[j];
}

// ---------------- node-parallel aggregation with 8-deep gather pipelining ----------
// one wave per node; lane = feature pair (float2). col/ew batch-loaded 64 at a
// time (coalesced) and broadcast via shfl; 8 independent row gathers in flight.
__global__ __launch_bounds__(256) void agg_kernel(const float* __restrict__ hw,
                                                  const int* __restrict__ row_ptr,
                                                  const int* __restrict__ col,
                                                  const float* __restrict__ ew,
                                                  const float* __restrict__ selfc,
                                                  const float* __restrict__ bias,
                                                  float* __restrict__ out, int n) {
    int node = blockIdx.x * 4 + (threadIdx.x >> 6);
    if (node >= n) return;
    int lane = threadIdx.x & 63;
    int beg = row_ptr[node], end = row_ptr[node + 1];
    float ax0 = 0.f, ay0 = 0.f, ax1 = 0.f, ay1 = 0.f;
    const size_t fo = (size_t)(lane * 2);
    for (int e0 = beg; e0 < end; e0 += 64) {
        int m = min(64, end - e0);
        int c_l = (lane < m) ? col[e0 + lane] : 0;
        float w_l = (lane < m) ? ew[e0 + lane] : 0.f;
        int j = 0;
        for (; j + 8 <= m; j += 8) {
            int c[8];
            float w[8];
            #pragma unroll
            for (int u = 0; u < 8; u++) {
                c[u] = __shfl(c_l, j + u);
                w[u] = __shfl(w_l, j + u);
            }
            float2 v[8];
            #pragma unroll
            for (int u = 0; u < 8; u++)
                v[u] = *(const float2*)&hw[(size_t)c[u] * HID + fo];
            #pragma unroll
            for (int u = 0; u < 8; u += 2) {
                ax0 += w[u] * v[u].x;
                ay0 += w[u] * v[u].y;
                ax1 += w[u + 1] * v[u + 1].x;
                ay1 += w[u + 1] * v[u + 1].y;
            }
        }
        for (; j < m; j++) {
            int cj = __shfl(c_l, j);
            float wj = __shfl(w_l, j);
            float2 v = *(const float2*)&hw[(size_t)cj * HID + fo];
            ax0 += wj * v.x;
            ay0 += wj * v.y;
        }
    }
    float sc = selfc[node];
    float2 hs = *(const float2*)&hw[(size_t)node * HID + fo];
    float2 b = *(const float2*)&bias[fo];
    float ox = fmaxf(ax0 + ax1 + sc * hs.x + b.x, 0.0f);
    float oy = fmaxf(ay0 + ay1 + sc * hs.y + b.y, 0.0f);
    *(float2*)&out[(size_t)node * HID + fo] = make_float2(ox, oy);
}

// ---------------- graph boundaries via binary search (batch is sorted) ---------
__global__ __launch_bounds__(128) void gbounds_kernel(const int* __restrict__ batch,
                                                      int* __restrict__ bnd,
                                                      int* __restrict__ gcnt) {
    int g = threadIdx.x;
    if (g <= N_GRAPHS) {
        int lo = 0, hi = N_NODES;
        while (lo < hi) {
            int mid = (lo + hi) >> 1;
            if (batch[mid] < g) lo = mid + 1;
            else hi = mid;
        }
        bnd[g] = lo;
    }
    __syncthreads();
    if (g < N_GRAPHS) gcnt[g] = bnd[g + 1] - bnd[g];
}

__global__ __launch_bounds__(128) void pool_kernel(const float* __restrict__ h,
                                                   const int* __restrict__ batch,
                                                   float* __restrict__ pooled, int n) {
    int f = threadIdx.x;
    int n0 = blockIdx.x * 64;
    if (n0 >= n) return;
    int n1 = min(n0 + 64, n);
    float acc = 0.f;
    int cur = batch[n0];
    for (int i = n0; i < n1; i++) {
        int b = batch[i];
        if (b != cur) {
            atomicAdd(&pooled[cur * HID + f], acc);
            acc = 0.f;
            cur = b;
        }
        acc += h[(size_t)i * HID + f];
    }
    atomicAdd(&pooled[cur * HID + f], acc);
}

// ---------------- head: mean, dense 128->10, log_softmax ----------------
__global__ __launch_bounds__(128) void final_kernel(const float* __restrict__ pooled,
                                                    const int* __restrict__ gcnt,
                                                    const float* __restrict__ Wout,
                                                    const float* __restrict__ bout,
                                                    float* __restrict__ out) {
    __shared__ float p[HID];
    __shared__ float lg[10];
    __shared__ float lsum;
    int g = blockIdx.x, t = threadIdx.x;
    float c = fmaxf((float)gcnt[g], 1.0f);
    p[t] = pooled[g * HID + t] / c;
    __syncthreads();
    if (t < 10) {
        float s = bout[t];
        for (int f = 0; f < HID; f++) s += p[f] * Wout[f * 10 + t];
        lg[t] = s;
    }
    __syncthreads();
    if (t == 0) {
        float m = lg[0];
        for (int ci = 1; ci < 10; ci++) m = fmaxf(m, lg[ci]);
        float se = 0.f;
        for (int ci = 0; ci < 10; ci++) se += expf(lg[ci] - m);
        lsum = m + logf(se);
    }
    __syncthreads();
    if (t < 10) out[g * 10 + t] = lg[t] - lsum;
}

extern "C" void kernel_launch(void* const* d_in, const int* in_sizes, int n_in,
                              void* d_out, int out_size, void* d_ws, size_t ws_size,
                              hipStream_t stream) {
    const float* x = (const float*)d_in[0];
    const int* ei = (const int*)d_in[1];
    const int* batch = (const int*)d_in[2];
    const float* W[5] = {(const float*)d_in[3], (const float*)d_in[5], (const float*)d_in[7],
                         (const float*)d_in[9], (const float*)d_in[11]};
    const float* B[5] = {(const float*)d_in[4], (const float*)d_in[6], (const float*)d_in[8],
                         (const float*)d_in[10], (const float*)d_in[12]};
    const float* Wout = (const float*)d_in[13];
    const float* bout = (const float*)d_in[14];
    float* out = (float*)d_out;

    const int* src = ei;
    const int* dst = ei + N_EDGES;

    char* ws = (char*)d_ws;
    size_t off = 0;
    auto alloc = [&](size_t bytes) -> char* {
        char* p = ws + off;
        off = (off + bytes + 255) & ~(size_t)255;
        return p;
    };
    int* cnt = (int*)alloc(N_NODES * 4);
    float* pooled = (float*)alloc(N_GRAPHS * HID * 4);
    size_t zero_span = off;  // cnt + pooled get memset to 0
    int* gcnt = (int*)alloc(N_GRAPHS * 4);
    int* bnd = (int*)alloc((N_GRAPHS + 1) * 4);
    int* row_ptr = (int*)alloc((N_NODES + 1) * 4);
    int* fill = (int*)alloc(N_NODES * 4);
    float* dis = (float*)alloc(N_NODES * 4);
    float* selfc = (float*)alloc(N_NODES * 4);
    int* bsum = (int*)alloc(128 * 4);
    int* bexcl = (int*)alloc(128 * 4);
    int* col = (int*)alloc((size_t)N_EDGES * 4);
    float* ew = (float*)alloc((size_t)N_EDGES * 4);
    float* h_a = (float*)alloc((size_t)N_NODES * HID * 4);
    float* h_b = (float*)alloc((size_t)N_NODES * HID * 4);

    hipMemsetAsync(d_ws, 0, zero_span, stream);

    int eb = (N_EDGES + 255) / 256;
    int nb = (N_NODES + 255) / 256;
    int sb = (N_NODES + 1023) / 1024;  // 98

    deg_kernel<<<eb, 256, 0, stream>>>(dst, cnt, N_EDGES);
    dis_kernel<<<nb, 256, 0, stream>>>(cnt, dis, selfc, N_NODES);
    scan_block_sum<<<sb, 1024, 0, stream>>>(cnt, bsum, N_NODES);
    scan_bsum<<<1, 64, 0, stream>>>(bsum, bexcl, row_ptr + N_NODES, sb);
    scan_final<<<sb, 1024, 0, stream>>>(cnt, bexcl, row_ptr, fill, N_NODES);
    csr_fill<<<eb, 256, 0, stream>>>(src, dst, dis, fill, col, ew, N_EDGES);
    gbounds_kernel<<<1, 128, 0, stream>>>(batch, bnd, gcnt);

    int gb = (N_NODES + 255) / 256;
    int ab = (N_NODES + 3) / 4;

    // layer 1: K=8
    gemm_kernel<8><<<gb, 256, 0, stream>>>(x, W[0], h_b, N_NODES);
    agg_kernel<<<ab, 256, 0, stream>>>(h_b, row_ptr, col, ew, selfc, B[0], h_a, N_NODES);
    // layers 2..5: K=128
    for (int l = 1; l < 5; l++) {
        gemm_kernel<128><<<gb, 256, 0, stream>>>(h_a, W[l], h_b, N_NODES);
        agg_kernel<<<ab, 256, 0, stream>>>(h_b, row_ptr, col, ew, selfc, B[l], h_a, N_NODES);
    }

    pool_kernel<<<(N_NODES + 63) / 64, 128, 0, stream>>>(h_a, batch, pooled, N_NODES);
    final_kernel<<<N_GRAPHS, 128, 0, stream>>>(pooled, gcnt, Wout, bout, out);
}

// Round 3
// 1382.095 us; speedup vs baseline: 2.2234x; 1.5416x over previous
//
#include <hip/hip_runtime.h>
#include <hip/hip_fp16.h>

#define N_NODES 100000
#define N_EDGES 3200000
#define N_GRAPHS 64
#define HID 128

// ---------------- degree histogram ----------------
__global__ void deg_kernel(const int* __restrict__ dst, int* __restrict__ cnt, int e) {
    int i = blockIdx.x * blockDim.x + threadIdx.x;
    if (i < e) atomicAdd(&cnt[dst[i]], 1);
}

__global__ void dis_kernel(const int* __restrict__ cnt, float* __restrict__ dis,
                           float* __restrict__ selfc, int n) {
    int i = blockIdx.x * blockDim.x + threadIdx.x;
    if (i < n) {
        float d = (float)cnt[i] + 1.0f;
        dis[i] = rsqrtf(d);
        selfc[i] = 1.0f / d;
    }
}

// ---------------- 3-kernel exclusive scan (for CSR row_ptr) ----------------
__global__ void scan_block_sum(const int* __restrict__ cnt, int* __restrict__ bsum, int n) {
    __shared__ int sdata[16];
    int i = blockIdx.x * 1024 + threadIdx.x;
    int v = (i < n) ? cnt[i] : 0;
    #pragma unroll
    for (int off = 32; off > 0; off >>= 1) v += __shfl_down(v, off, 64);
    int wid = threadIdx.x >> 6, lane = threadIdx.x & 63;
    if (lane == 0) sdata[wid] = v;
    __syncthreads();
    if (threadIdx.x == 0) {
        int s = 0;
        for (int w = 0; w < 16; w++) s += sdata[w];
        bsum[blockIdx.x] = s;
    }
}

__global__ void scan_bsum(int* __restrict__ bsum, int* __restrict__ bexcl,
                          int* __restrict__ row_ptr_last, int nb) {
    if (threadIdx.x == 0 && blockIdx.x == 0) {
        int s = 0;
        for (int b = 0; b < nb; b++) { bexcl[b] = s; s += bsum[b]; }
        row_ptr_last[0] = s;  // row_ptr[N] == E
    }
}

__global__ void scan_final(const int* __restrict__ cnt, const int* __restrict__ bexcl,
                           int* __restrict__ row_ptr, int* __restrict__ fill, int n) {
    __shared__ int buf[1024];
    int t = threadIdx.x;
    int i = blockIdx.x * 1024 + t;
    int v = (i < n) ? cnt[i] : 0;
    buf[t] = v;
    __syncthreads();
    for (int off = 1; off < 1024; off <<= 1) {
        int x = (t >= off) ? buf[t - off] : 0;
        __syncthreads();
        buf[t] += x;
        __syncthreads();
    }
    int excl = buf[t] - v + bexcl[blockIdx.x];
    if (i < n) { row_ptr[i] = excl; fill[i] = excl; }
}

// ---------------- CSR bucket fill: packed (col, ew) single 8B store ----------------
__global__ void csr_fill(const int* __restrict__ src, const int* __restrict__ dst,
                         const float* __restrict__ dis, int* __restrict__ fill,
                         int2* __restrict__ pck, int e) {
    int i = blockIdx.x * blockDim.x + threadIdx.x;
    if (i < e) {
        int s = src[i], d = dst[i];
        int pos = atomicAdd(&fill[d], 1);
        int2 p;
        p.x = s;
        p.y = __float_as_int(dis[s] * dis[d]);
        pck[pos] = p;
    }
}

__device__ inline uint2 f4_to_h4(float4 v) {
    __half2 a = __floats2half2_rn(v.x, v.y);
    __half2 b = __floats2half2_rn(v.z, v.w);
    uint2 r;
    r.x = *(unsigned*)&a;
    r.y = *(unsigned*)&b;
    return r;
}

// ---------------- GEMM layer 1: A[N x 8] fp32 @ W[8 x 128] -> fp16 ----------------
__global__ __launch_bounds__(256) void gemm_k8(const float* __restrict__ A,
                                               const float* __restrict__ W,
                                               __half* __restrict__ out, int n) {
    __shared__ float4 Ws[8 * 32];
    const float4* W4 = (const float4*)W;
    for (int i = threadIdx.x; i < 8 * 32; i += 256) Ws[i] = W4[i];
    __syncthreads();
    int r = blockIdx.x * 256 + threadIdx.x;
    if (r >= n) return;
    float4 acc[32];
    #pragma unroll
    for (int j = 0; j < 32; j++) acc[j] = make_float4(0.f, 0.f, 0.f, 0.f);
    const float4* Arow = (const float4*)(A + (size_t)r * 8);
    float4 a0 = Arow[0], a1 = Arow[1];
    float av[8] = {a0.x, a0.y, a0.z, a0.w, a1.x, a1.y, a1.z, a1.w};
    #pragma unroll
    for (int kk = 0; kk < 8; kk++) {
        float a = av[kk];
        #pragma unroll
        for (int j = 0; j < 32; j++) {
            float4 w = Ws[kk * 32 + j];
            acc[j].x += a * w.x;
            acc[j].y += a * w.y;
            acc[j].z += a * w.z;
            acc[j].w += a * w.w;
        }
    }
    uint2* o = (uint2*)(out + (size_t)r * HID);
    #pragma unroll
    for (int j = 0; j < 32; j++) o[j] = f4_to_h4(acc[j]);
}

// ---------------- GEMM layers 2..5: A[N x 128] fp16 @ W[128 x 128] -> fp16 --------
__global__ __launch_bounds__(256) void gemm_k128(const __half* __restrict__ A,
                                                 const float* __restrict__ W,
                                                 __half* __restrict__ out, int n) {
    __shared__ float4 Ws[128 * 32];  // 64 KB
    const float4* W4 = (const float4*)W;
    for (int i = threadIdx.x; i < 128 * 32; i += 256) Ws[i] = W4[i];
    __syncthreads();
    int r = blockIdx.x * 256 + threadIdx.x;
    if (r >= n) return;
    float4 acc[32];
    #pragma unroll
    for (int j = 0; j < 32; j++) acc[j] = make_float4(0.f, 0.f, 0.f, 0.f);
    const uint2* Arow = (const uint2*)(A + (size_t)r * 128);
    #pragma unroll 2
    for (int k0 = 0; k0 < 32; k0++) {
        uint2 raw = Arow[k0];
        __half2 h01 = *(__half2*)&raw.x;
        __half2 h23 = *(__half2*)&raw.y;
        float2 f01 = __half22float2(h01);
        float2 f23 = __half22float2(h23);
        float av[4] = {f01.x, f01.y, f23.x, f23.y};
        #pragma unroll
        for (int kk = 0; kk < 4; kk++) {
            float a = av[kk];
            #pragma unroll
            for (int j = 0; j < 32; j++) {
                float4 w = Ws[(k0 * 4 + kk) * 32 + j];
                acc[j].x += a * w.x;
                acc[j].y += a * w.y;
                acc[j].z += a * w.z;
                acc[j].w += a * w.w;
            }
        }
    }
    uint2* o = (uint2*)(out + (size_t)r * HID);
    #pragma unroll
    for (int j = 0; j < 32; j++) o[j] = f4_to_h4(acc[j]);
}

// ---------------- aggregation: one wave/node, 2 edges per gather instr ----------
// lanes 0-31 gather edge A's fp16 row (half4/lane), lanes 32-63 edge B's row.
// acc fp32; cross-half combine via shfl_xor(32); fused self-loop + bias + relu.
__global__ __launch_bounds__(256) void agg_kernel(const __half* __restrict__ hw,
                                                  const int* __restrict__ row_ptr,
                                                  const int2* __restrict__ pck,
                                                  const float* __restrict__ selfc,
                                                  const float* __restrict__ bias,
                                                  __half* __restrict__ out, int n) {
    int node = blockIdx.x * 4 + (threadIdx.x >> 6);
    if (node >= n) return;
    int lane = threadIdx.x & 63;
    int half_id = lane >> 5;
    int fl = (lane & 31) * 4;  // 4 features per lane
    int beg = row_ptr[node], end = row_ptr[node + 1];
    float a0 = 0.f, a1 = 0.f, a2 = 0.f, a3 = 0.f;
    for (int e0 = beg; e0 < end; e0 += 64) {
        int m = min(64, end - e0);
        int cl = 0;
        float wl = 0.f;
        if (lane < m) {
            int2 p = pck[e0 + lane];
            cl = p.x;
            wl = __int_as_float(p.y);
        }
        int pairs = (m + 1) >> 1;
        int j = 0;
        for (; j + 4 <= pairs; j += 4) {  // 8 edges per iter, 4 gathers in flight
            int c[4];
            float w[4];
            #pragma unroll
            for (int u = 0; u < 4; u++) {
                int idx = 2 * (j + u) + half_id;
                c[u] = __shfl(cl, idx);
                w[u] = __shfl(wl, idx);
            }
            uint2 raw[4];
            #pragma unroll
            for (int u = 0; u < 4; u++)
                raw[u] = *(const uint2*)(hw + (size_t)c[u] * HID + fl);
            #pragma unroll
            for (int u = 0; u < 4; u++) {
                float2 f01 = __half22float2(*(__half2*)&raw[u].x);
                float2 f23 = __half22float2(*(__half2*)&raw[u].y);
                a0 += w[u] * f01.x;
                a1 += w[u] * f01.y;
                a2 += w[u] * f23.x;
                a3 += w[u] * f23.y;
            }
        }
        for (; j < pairs; j++) {
            int idx = 2 * j + half_id;
            int c = __shfl(cl, idx);
            float w = __shfl(wl, idx);
            uint2 raw = *(const uint2*)(hw + (size_t)c * HID + fl);
            float2 f01 = __half22float2(*(__half2*)&raw.x);
            float2 f23 = __half22float2(*(__half2*)&raw.y);
            a0 += w * f01.x;
            a1 += w * f01.y;
            a2 += w * f23.x;
            a3 += w * f23.y;
        }
    }
    a0 += __shfl_xor(a0, 32);
    a1 += __shfl_xor(a1, 32);
    a2 += __shfl_xor(a2, 32);
    a3 += __shfl_xor(a3, 32);
    if (lane < 32) {
        float sc = selfc[node];
        uint2 hraw = *(const uint2*)(hw + (size_t)node * HID + fl);
        float2 s01 = __half22float2(*(__half2*)&hraw.x);
        float2 s23 = __half22float2(*(__half2*)&hraw.y);
        float4 b4 = *(const float4*)(bias + fl);
        float o0 = fmaxf(a0 + sc * s01.x + b4.x, 0.f);
        float o1 = fmaxf(a1 + sc * s01.y + b4.y, 0.f);
        float o2 = fmaxf(a2 + sc * s23.x + b4.z, 0.f);
        float o3 = fmaxf(a3 + sc * s23.y + b4.w, 0.f);
        __half2 q01 = __floats2half2_rn(o0, o1);
        __half2 q23 = __floats2half2_rn(o2, o3);
        uint2 o;
        o.x = *(unsigned*)&q01;
        o.y = *(unsigned*)&q23;
        *(uint2*)(out + (size_t)node * HID + fl) = o;
    }
}

// ---------------- graph boundaries via binary search (batch is sorted) ---------
__global__ __launch_bounds__(128) void gbounds_kernel(const int* __restrict__ batch,
                                                      int* __restrict__ bnd,
                                                      int* __restrict__ gcnt) {
    int g = threadIdx.x;
    if (g <= N_GRAPHS) {
        int lo = 0, hi = N_NODES;
        while (lo < hi) {
            int mid = (lo + hi) >> 1;
            if (batch[mid] < g) lo = mid + 1;
            else hi = mid;
        }
        bnd[g] = lo;
    }
    __syncthreads();
    if (g < N_GRAPHS) gcnt[g] = bnd[g + 1] - bnd[g];
}

__global__ __launch_bounds__(128) void pool_kernel(const __half* __restrict__ h,
                                                   const int* __restrict__ batch,
                                                   float* __restrict__ pooled, int n) {
    int f = threadIdx.x;
    int n0 = blockIdx.x * 64;
    if (n0 >= n) return;
    int n1 = min(n0 + 64, n);
    float acc = 0.f;
    int cur = batch[n0];
    for (int i = n0; i < n1; i++) {
        int b = batch[i];
        if (b != cur) {
            atomicAdd(&pooled[cur * HID + f], acc);
            acc = 0.f;
            cur = b;
        }
        acc += __half2float(h[(size_t)i * HID + f]);
    }
    atomicAdd(&pooled[cur * HID + f], acc);
}

// ---------------- head: mean, dense 128->10, log_softmax ----------------
__global__ __launch_bounds__(128) void final_kernel(const float* __restrict__ pooled,
                                                    const int* __restrict__ gcnt,
                                                    const float* __restrict__ Wout,
                                                    const float* __restrict__ bout,
                                                    float* __restrict__ out) {
    __shared__ float p[HID];
    __shared__ float lg[10];
    __shared__ float lsum;
    int g = blockIdx.x, t = threadIdx.x;
    float c = fmaxf((float)gcnt[g], 1.0f);
    p[t] = pooled[g * HID + t] / c;
    __syncthreads();
    if (t < 10) {
        float s = bout[t];
        for (int f = 0; f < HID; f++) s += p[f] * Wout[f * 10 + t];
        lg[t] = s;
    }
    __syncthreads();
    if (t == 0) {
        float m = lg[0];
        for (int ci = 1; ci < 10; ci++) m = fmaxf(m, lg[ci]);
        float se = 0.f;
        for (int ci = 0; ci < 10; ci++) se += expf(lg[ci] - m);
        lsum = m + logf(se);
    }
    __syncthreads();
    if (t < 10) out[g * 10 + t] = lg[t] - lsum;
}

extern "C" void kernel_launch(void* const* d_in, const int* in_sizes, int n_in,
                              void* d_out, int out_size, void* d_ws, size_t ws_size,
                              hipStream_t stream) {
    const float* x = (const float*)d_in[0];
    const int* ei = (const int*)d_in[1];
    const int* batch = (const int*)d_in[2];
    const float* W[5] = {(const float*)d_in[3], (const float*)d_in[5], (const float*)d_in[7],
                         (const float*)d_in[9], (const float*)d_in[11]};
    const float* B[5] = {(const float*)d_in[4], (const float*)d_in[6], (const float*)d_in[8],
                         (const float*)d_in[10], (const float*)d_in[12]};
    const float* Wout = (const float*)d_in[13];
    const float* bout = (const float*)d_in[14];
    float* out = (float*)d_out;

    const int* src = ei;
    const int* dst = ei + N_EDGES;

    char* ws = (char*)d_ws;
    size_t off = 0;
    auto alloc = [&](size_t bytes) -> char* {
        char* p = ws + off;
        off = (off + bytes + 255) & ~(size_t)255;
        return p;
    };
    int* cnt = (int*)alloc(N_NODES * 4);
    float* pooled = (float*)alloc(N_GRAPHS * HID * 4);
    size_t zero_span = off;  // cnt + pooled get memset to 0
    int* gcnt = (int*)alloc(N_GRAPHS * 4);
    int* bnd = (int*)alloc((N_GRAPHS + 1) * 4);
    int* row_ptr = (int*)alloc((N_NODES + 1) * 4);
    int* fill = (int*)alloc(N_NODES * 4);
    float* dis = (float*)alloc(N_NODES * 4);
    float* selfc = (float*)alloc(N_NODES * 4);
    int* bsum = (int*)alloc(128 * 4);
    int* bexcl = (int*)alloc(128 * 4);
    int2* pck = (int2*)alloc((size_t)N_EDGES * 8);
    __half* h_a = (__half*)alloc((size_t)N_NODES * HID * 2);
    __half* h_b = (__half*)alloc((size_t)N_NODES * HID * 2);

    hipMemsetAsync(d_ws, 0, zero_span, stream);

    int eb = (N_EDGES + 255) / 256;
    int nb = (N_NODES + 255) / 256;
    int sb = (N_NODES + 1023) / 1024;  // 98

    deg_kernel<<<eb, 256, 0, stream>>>(dst, cnt, N_EDGES);
    dis_kernel<<<nb, 256, 0, stream>>>(cnt, dis, selfc, N_NODES);
    scan_block_sum<<<sb, 1024, 0, stream>>>(cnt, bsum, N_NODES);
    scan_bsum<<<1, 64, 0, stream>>>(bsum, bexcl, row_ptr + N_NODES, sb);
    scan_final<<<sb, 1024, 0, stream>>>(cnt, bexcl, row_ptr, fill, N_NODES);
    csr_fill<<<eb, 256, 0, stream>>>(src, dst, dis, fill, pck, N_EDGES);
    gbounds_kernel<<<1, 128, 0, stream>>>(batch, bnd, gcnt);

    int gb = (N_NODES + 255) / 256;
    int ab = (N_NODES + 3) / 4;

    // layer 1: K=8 (fp32 input)
    gemm_k8<<<gb, 256, 0, stream>>>(x, W[0], h_b, N_NODES);
    agg_kernel<<<ab, 256, 0, stream>>>(h_b, row_ptr, pck, selfc, B[0], h_a, N_NODES);
    // layers 2..5: K=128 (fp16 input)
    for (int l = 1; l < 5; l++) {
        gemm_k128<<<gb, 256, 0, stream>>>(h_a, W[l], h_b, N_NODES);
        agg_kernel<<<ab, 256, 0, stream>>>(h_b, row_ptr, pck, selfc, B[l], h_a, N_NODES);
    }

    pool_kernel<<<(N_NODES + 63) / 64, 128, 0, stream>>>(h_a, batch, pooled, N_NODES);
    final_kernel<<<N_GRAPHS, 128, 0, stream>>>(pooled, gcnt, Wout, bout, out);
}